// Round 2
// baseline (489.518 us; speedup 1.0000x reference)
//
#include <hip/hip_runtime.h>

typedef unsigned short u16;
typedef __attribute__((ext_vector_type(8))) short frag8;
typedef __attribute__((ext_vector_type(4))) float f32x4;

static constexpr int C = 768;
static constexpr int F3 = 2304;      // 3*C
static constexpr int MROWS = 32768;  // B*T*H*W
static constexpr float LNEPS = 1e-5f;

__device__ __forceinline__ float bfu2f(u16 u){
  union { unsigned u; float f; } x; x.u = (unsigned)u << 16; return x.f;
}
__device__ __forceinline__ u16 f2bfu(float f){
  union { float f; unsigned u; } x; x.f = f;
  unsigned r = x.u + 0x7fffu + ((x.u >> 16) & 1u);   // RNE bf16
  return (u16)(r >> 16);
}

__device__ __forceinline__ void gload16(const void* g, void* l){
  __builtin_amdgcn_global_load_lds(
      (const __attribute__((address_space(1))) void*)g,
      (__attribute__((address_space(3))) void*)l, 16, 0, 0);
}

// ---------------- fp32 -> bf16 weight conversion ----------------
__global__ __launch_bounds__(256) void cvt_bf16(const float* __restrict__ src,
                                                u16* __restrict__ dst, int n){
  int i = blockIdx.x * 256 + threadIdx.x;
  if (i < n) dst[i] = f2bfu(src[i]);
}

// ---------------- LN1: fp32 x -> bf16 y ----------------
__global__ __launch_bounds__(256) void ln1_kernel(const float* __restrict__ x,
    const float* __restrict__ w, const float* __restrict__ b, u16* __restrict__ y){
  const int lane = threadIdx.x & 63, wid = threadIdx.x >> 6;
  const size_t row = (size_t)blockIdx.x * 4 + wid;
  const float4* xr = reinterpret_cast<const float4*>(x + row * C);
  float v[12];
  #pragma unroll
  for (int j = 0; j < 3; j++){
    float4 t = xr[lane + j*64];
    v[j*4+0]=t.x; v[j*4+1]=t.y; v[j*4+2]=t.z; v[j*4+3]=t.w;
  }
  float s = 0.f, ss = 0.f;
  #pragma unroll
  for (int j = 0; j < 12; j++){ s += v[j]; ss += v[j]*v[j]; }
  #pragma unroll
  for (int o = 32; o; o >>= 1){ s += __shfl_xor(s, o, 64); ss += __shfl_xor(ss, o, 64); }
  const float mu = s * (1.f/768.f);
  const float rs = rsqrtf(ss*(1.f/768.f) - mu*mu + LNEPS);
  ushort4* yr = reinterpret_cast<ushort4*>(y + row * C);
  const float4* wv = reinterpret_cast<const float4*>(w);
  const float4* bv = reinterpret_cast<const float4*>(b);
  #pragma unroll
  for (int j = 0; j < 3; j++){
    float4 wj = wv[lane + j*64], bj = bv[lane + j*64];
    ushort4 o4;
    o4.x = f2bfu((v[j*4+0]-mu)*rs*wj.x + bj.x);
    o4.y = f2bfu((v[j*4+1]-mu)*rs*wj.y + bj.y);
    o4.z = f2bfu((v[j*4+2]-mu)*rs*wj.z + bj.z);
    o4.w = f2bfu((v[j*4+3]-mu)*rs*wj.w + bj.w);
    yr[lane + j*64] = o4;
  }
}

// ---------------- GEMM: C[m,n] = sum_k A[m,k]*B[n,k]  (B^T layout) ----------------
// LDS layout: 8 subtiles per operand tile; subtile s = rows 16s..16s+15 of the
// 128x32 K-step tile, stored in MFMA-fragment lane order: lane l <-> element
// (row = 16s + (l&15), k = (l>>4)*8 .. +8). ds_read_b128 is then 64x16B fully
// contiguous (conflict-free); global_load_lds keeps a linear LDS dest and the
// per-lane GLOBAL source address carries the shuffle (m104/m173 pattern).
// MODE 0: out = bf16(acc + bias)            (qkv projection)
// MODE 1: out = fp32(acc + bias + resid)    (out projection + residual)
template<int MODE>
__global__ __launch_bounds__(256) void gemm_bt(
    const u16* __restrict__ A, const u16* __restrict__ Bw,
    const float* __restrict__ bias, const float* __restrict__ resid,
    void* __restrict__ Cout, int Ndim, int K)
{
  __shared__ __align__(16) u16 buf[(MODE == 0) ? 16384 : 8192];
  u16* lA = buf;            // 4096 u16 = 8 KB (8 subtiles x 1 KB)
  u16* lB = buf + 4096;     // 8 KB
  u16* lC = buf;            // MODE0 epilogue: full 32 KB (after final barrier)

  const int tid = threadIdx.x;
  const int lane = tid & 63, wid = tid >> 6;
  const int ntn = Ndim >> 7;
  // T1: bijective XCD swizzle (grid % 8 == 0 for both instantiations)
  const int cpx = gridDim.x >> 3;
  const int wg = (blockIdx.x & 7) * cpx + (blockIdx.x >> 3);
  const int bm = wg / ntn, bn = wg % ntn;
  const int m0 = bm << 7, n0 = bn << 7;
  const int wr = wid >> 1, wc = wid & 1;

  const int fr = lane & 15, kq = lane >> 4;

  // staging sources: wave wid owns subtiles 2*wid, 2*wid+1 of each operand
  const u16* gA0 = A  + (size_t)(m0 + wid*32 + fr) * K + kq*8;
  const u16* gA1 = gA0 + 16*(size_t)K;
  const u16* gB0 = Bw + (size_t)(n0 + wid*32 + fr) * K + kq*8;
  const u16* gB1 = gB0 + 16*(size_t)K;
  char* dA0 = (char*)lA + 2*wid*1024;
  char* dB0 = (char*)lB + 2*wid*1024;

  f32x4 acc[4][4] = {};

  const char* paBase = (const char*)lA + (wr*4)*1024 + lane*16;
  const char* pbBase = (const char*)lB + (wc*4)*1024 + lane*16;

  for (int kt = 0; kt < K; kt += 32){
    gload16(gA0 + kt, dA0);
    gload16(gA1 + kt, dA0 + 1024);
    gload16(gB0 + kt, dB0);
    gload16(gB1 + kt, dB0 + 1024);
    __syncthreads();   // compiler drains vmcnt before barrier
    frag8 af[4], bfr[4];
    #pragma unroll
    for (int i = 0; i < 4; i++){
      af[i]  = *reinterpret_cast<const frag8*>(paBase + i*1024);
      bfr[i] = *reinterpret_cast<const frag8*>(pbBase + i*1024);
    }
    #pragma unroll
    for (int i = 0; i < 4; i++)
      #pragma unroll
      for (int j = 0; j < 4; j++)
        acc[i][j] = __builtin_amdgcn_mfma_f32_16x16x32_bf16(af[i], bfr[j], acc[i][j], 0, 0, 0);
    __syncthreads();
  }

  // epilogue: C/D frag layout col=lane&15, row=(lane>>4)*4+r  [m89-verified]
  const int er = (lane >> 4) * 4, ec = lane & 15;
  if (MODE == 0){
    // stage bf16 tile in LDS, then coalesced dwordx4 stores
    #pragma unroll
    for (int j = 0; j < 4; j++){
      const float bv = bias[n0 + wc*64 + j*16 + ec];
      #pragma unroll
      for (int i = 0; i < 4; i++)
        #pragma unroll
        for (int r = 0; r < 4; r++)
          lC[(wr*64 + i*16 + er + r)*128 + wc*64 + j*16 + ec] = f2bfu(acc[i][j][r] + bv);
    }
    __syncthreads();
    const int row = tid >> 1, h = tid & 1;
    const uint4* src = reinterpret_cast<const uint4*>(&lC[row*128 + h*64]);
    uint4* dst = reinterpret_cast<uint4*>((u16*)Cout + (size_t)(m0 + row) * Ndim + n0 + h*64);
    #pragma unroll
    for (int q = 0; q < 8; q++) dst[q] = src[q];
  } else {
    #pragma unroll
    for (int j = 0; j < 4; j++){
      const int col = n0 + wc*64 + j*16 + ec;
      const float bv = bias[col];
      #pragma unroll
      for (int i = 0; i < 4; i++){
        #pragma unroll
        for (int r = 0; r < 4; r++){
          const size_t row = (size_t)(m0 + wr*64 + i*16 + er + r);
          ((float*)Cout)[row * Ndim + col] = acc[i][j][r] + bv + resid[row * Ndim + col];
        }
      }
    }
  }
}

// ---------------- attention over T=16, one wave per (b,h,w,head) ----------------
// qkv row layout per head n: f = n*192 + [0:64)=q [64:128)=k [128:192)=v
// output o (16x64) overwrites the v-slots (already staged to LDS before write).
__global__ __launch_bounds__(64) void attn_kernel(u16* __restrict__ qkv){
  __shared__ __align__(16) u16 sq[16][72];
  __shared__ __align__(16) u16 sk[16][72];
  __shared__ __align__(16) u16 sv[16][72];
  __shared__ float sp[16][17];
  const int lane = threadIdx.x;
  int bid = blockIdx.x;
  const int n = bid % 12; bid /= 12;
  const int w = bid % 32; bid /= 32;
  const int h = bid % 32; const int b = bid / 32;
  u16* base = qkv + ((size_t)(b*16384 + h*32 + w)) * F3 + n * 192;
  const size_t tstride = (size_t)1024 * F3;   // t-step = 1024 rows

  #pragma unroll
  for (int i = 0; i < 6; i++){
    const int e8 = lane + i*64;
    const int t = e8 / 24, ck = e8 % 24;
    uint4 val = *reinterpret_cast<const uint4*>(base + (size_t)t*tstride + ck*8);
    u16* dst = (ck < 8) ? &sq[t][ck*8] : (ck < 16) ? &sk[t][(ck-8)*8] : &sv[t][(ck-16)*8];
    *reinterpret_cast<uint4*>(dst) = val;
  }
  __syncthreads();

  const int g = lane >> 4, sj = lane & 15;
  float accv[4] = {0.f, 0.f, 0.f, 0.f};
  #pragma unroll
  for (int dc = 0; dc < 8; dc++){
    union { uint4 u; u16 s[8]; } kc;
    kc.u = *reinterpret_cast<const uint4*>(&sk[sj][dc*8]);
    #pragma unroll
    for (int i = 0; i < 4; i++){
      union { uint4 u; u16 s[8]; } qc;
      qc.u = *reinterpret_cast<const uint4*>(&sq[g + i*4][dc*8]);
      #pragma unroll
      for (int e = 0; e < 8; e++)
        accv[i] += bfu2f(qc.s[e]) * bfu2f(kc.s[e]);
    }
  }
  #pragma unroll
  for (int i = 0; i < 4; i++){
    float sc = accv[i] * 0.125f;
    float mx = sc;
    #pragma unroll
    for (int o = 1; o < 16; o <<= 1) mx = fmaxf(mx, __shfl_xor(mx, o, 16));
    float p = __expf(sc - mx);
    float sm = p;
    #pragma unroll
    for (int o = 1; o < 16; o <<= 1) sm += __shfl_xor(sm, o, 16);
    sp[g + i*4][sj] = p / sm;
  }
  __syncthreads();

  #pragma unroll
  for (int t = 0; t < 16; t++){
    float o = 0.f;
    #pragma unroll
    for (int s = 0; s < 16; s++) o += sp[t][s] * bfu2f(sv[s][lane]);
    base[(size_t)t*tstride + 128 + lane] = f2bfu(o);
  }
}

// ---------------- LN2: reads attention output from v-slots of qkv ----------------
__global__ __launch_bounds__(256) void ln2_kernel(const u16* __restrict__ qkv,
    const float* __restrict__ w, const float* __restrict__ b, u16* __restrict__ y2){
  const int lane = threadIdx.x & 63, wid = threadIdx.x >> 6;
  const size_t row = (size_t)blockIdx.x * 4 + wid;
  const u16* src = qkv + row * F3 + 128;
  float v[12];
  #pragma unroll
  for (int j = 0; j < 12; j++) v[j] = bfu2f(src[j*192 + lane]);   // c = j*64+lane
  float s = 0.f, ss = 0.f;
  #pragma unroll
  for (int j = 0; j < 12; j++){ s += v[j]; ss += v[j]*v[j]; }
  #pragma unroll
  for (int o = 32; o; o >>= 1){ s += __shfl_xor(s, o, 64); ss += __shfl_xor(ss, o, 64); }
  const float mu = s * (1.f/768.f);
  const float rs = rsqrtf(ss*(1.f/768.f) - mu*mu + LNEPS);
  #pragma unroll
  for (int j = 0; j < 12; j++){
    const int c = j*64 + lane;
    y2[row * C + c] = f2bfu((v[j]-mu)*rs*w[c] + b[c]);
  }
}

extern "C" void kernel_launch(void* const* d_in, const int* in_sizes, int n_in,
                              void* d_out, int out_size, void* d_ws, size_t ws_size,
                              hipStream_t stream){
  const float* x    = (const float*)d_in[0];
  const float* ln1w = (const float*)d_in[1];
  const float* ln1b = (const float*)d_in[2];
  const float* Wqkv = (const float*)d_in[3];
  const float* bqkv = (const float*)d_in[4];
  const float* ln2w = (const float*)d_in[5];
  const float* ln2b = (const float*)d_in[6];
  const float* Wout = (const float*)d_in[7];
  const float* bout = (const float*)d_in[8];
  float* out = (float*)d_out;

  char* ws = (char*)d_ws;
  u16* qkv = (u16*)ws;                       // 32768*2304*2 = 150,994,944 B
  u16* y   = (u16*)(ws + 150994944);         // 32768*768*2  =  50,331,648 B (y1, then y2)
  u16* wq  = (u16*)(ws + 201326592);         // 2304*768*2   =   3,538,944 B
  u16* wo  = (u16*)(ws + 204865536);         // 768*768*2    =   1,179,648 B  (total 206,045,184)

  cvt_bf16<<<(F3*C + 255)/256, 256, 0, stream>>>(Wqkv, wq, F3*C);
  cvt_bf16<<<(C*C + 255)/256, 256, 0, stream>>>(Wout, wo, C*C);
  ln1_kernel<<<MROWS/4, 256, 0, stream>>>(x, ln1w, ln1b, y);
  gemm_bt<0><<<(MROWS/128)*(F3/128), 256, 0, stream>>>(y, wq, bqkv, nullptr, qkv, F3, C);
  attn_kernel<<<2*32*32*12, 64, 0, stream>>>(qkv);
  ln2_kernel<<<MROWS/4, 256, 0, stream>>>(qkv, ln2w, ln2b, y);
  gemm_bt<1><<<(MROWS/128)*(C/128), 256, 0, stream>>>(y, wo, bout, x, out, C, C);
}

// Round 3
// 428.128 us; speedup vs baseline: 1.1434x; 1.1434x over previous
//
#include <hip/hip_runtime.h>

typedef unsigned short u16;
typedef __attribute__((ext_vector_type(8))) short frag8;
typedef __attribute__((ext_vector_type(4))) float f32x4;

static constexpr int C = 768;
static constexpr int F3 = 2304;      // 3*C
static constexpr int MROWS = 32768;  // B*T*H*W
static constexpr float LNEPS = 1e-5f;

__device__ __forceinline__ float bfu2f(u16 u){
  union { unsigned u; float f; } x; x.u = (unsigned)u << 16; return x.f;
}
__device__ __forceinline__ u16 f2bfu(float f){
  union { float f; unsigned u; } x; x.f = f;
  unsigned r = x.u + 0x7fffu + ((x.u >> 16) & 1u);   // RNE bf16
  return (u16)(r >> 16);
}

__device__ __forceinline__ void gload16(const void* g, void* l){
  __builtin_amdgcn_global_load_lds(
      (const __attribute__((address_space(1))) void*)g,
      (__attribute__((address_space(3))) void*)l, 16, 0, 0);
}

// ---------------- fp32 -> bf16 weight conversion ----------------
__global__ __launch_bounds__(256) void cvt_bf16(const float* __restrict__ src,
                                                u16* __restrict__ dst, int n){
  int i = blockIdx.x * 256 + threadIdx.x;
  if (i < n) dst[i] = f2bfu(src[i]);
}

// ---------------- LN1: fp32 x -> bf16 y ----------------
__global__ __launch_bounds__(256) void ln1_kernel(const float* __restrict__ x,
    const float* __restrict__ w, const float* __restrict__ b, u16* __restrict__ y){
  const int lane = threadIdx.x & 63, wid = threadIdx.x >> 6;
  const size_t row = (size_t)blockIdx.x * 4 + wid;
  const float4* xr = reinterpret_cast<const float4*>(x + row * C);
  float v[12];
  #pragma unroll
  for (int j = 0; j < 3; j++){
    float4 t = xr[lane + j*64];
    v[j*4+0]=t.x; v[j*4+1]=t.y; v[j*4+2]=t.z; v[j*4+3]=t.w;
  }
  float s = 0.f, ss = 0.f;
  #pragma unroll
  for (int j = 0; j < 12; j++){ s += v[j]; ss += v[j]*v[j]; }
  #pragma unroll
  for (int o = 32; o; o >>= 1){ s += __shfl_xor(s, o, 64); ss += __shfl_xor(ss, o, 64); }
  const float mu = s * (1.f/768.f);
  const float rs = rsqrtf(ss*(1.f/768.f) - mu*mu + LNEPS);
  ushort4* yr = reinterpret_cast<ushort4*>(y + row * C);
  const float4* wv = reinterpret_cast<const float4*>(w);
  const float4* bv = reinterpret_cast<const float4*>(b);
  #pragma unroll
  for (int j = 0; j < 3; j++){
    float4 wj = wv[lane + j*64], bj = bv[lane + j*64];
    ushort4 o4;
    o4.x = f2bfu((v[j*4+0]-mu)*rs*wj.x + bj.x);
    o4.y = f2bfu((v[j*4+1]-mu)*rs*wj.y + bj.y);
    o4.z = f2bfu((v[j*4+2]-mu)*rs*wj.z + bj.z);
    o4.w = f2bfu((v[j*4+3]-mu)*rs*wj.w + bj.w);
    yr[lane + j*64] = o4;
  }
}

// ---------------- GEMM: C[m,n] = sum_k A[m,k]*B[n,k]  (B^T layout) ----------------
// Subtile = 16 rows x 32 k (u16) = 64 chunks of 16B; chunk c=(r,q), q=k-chunk.
// Swizzle sigma: slot p = ((r ^ ((r>>2)&1))<<2) | (q ^ (r&3)).
//  - store: lane l (slot l) fetches global chunk sigma^-1(l): quads of lanes
//    cover one contiguous 64B row segment (coalesced);
//  - read: lane l reads slot sigma(l&15, l>>4): per-16-lane phase hits all 8
//    bank groups evenly (conflict-free ds_read_b128).
// MODE 0: out = bf16(acc + bias)            (qkv projection)
// MODE 1: out = fp32(acc + bias + resid)    (out projection + residual)
template<int MODE>
__global__ __launch_bounds__(256) void gemm_bt(
    const u16* __restrict__ A, const u16* __restrict__ Bw,
    const float* __restrict__ bias, const float* __restrict__ resid,
    void* __restrict__ Cout, int Ndim, int K)
{
  __shared__ __align__(16) u16 buf[(MODE == 0) ? 16384 : 8192];
  u16* lA = buf;            // 8 KB (8 subtiles x 1 KB)
  u16* lB = buf + 4096;     // 8 KB
  u16* lC = buf;            // MODE0 epilogue reuses all 32 KB after final barrier

  const int tid = threadIdx.x;
  const int lane = tid & 63, wid = tid >> 6;
  const int ntn = Ndim >> 7;
  // T1: bijective XCD swizzle (grid % 8 == 0 for both instantiations)
  const int cpx = gridDim.x >> 3;
  const int wg = (blockIdx.x & 7) * cpx + (blockIdx.x >> 3);
  const int bm = wg / ntn, bn = wg % ntn;
  const int m0 = bm << 7, n0 = bn << 7;
  const int wr = wid >> 1, wc = wid & 1;

  // ---- staging source (sigma^-1): lane l -> (row rr, kchunk qq) of subtile
  const int rp = lane >> 2;                 // slot row-field
  const int rr = rp ^ ((rp >> 2) & 1);      // actual row in subtile
  const int qq = (lane & 3) ^ (rr & 3);     // actual k-chunk
  const u16* gA0 = A  + (size_t)(m0 + wid*32 + rr) * K + qq*8;
  const u16* gA1 = gA0 + 16*(size_t)K;
  const u16* gB0 = Bw + (size_t)(n0 + wid*32 + rr) * K + qq*8;
  const u16* gB1 = gB0 + 16*(size_t)K;
  char* dA0 = (char*)lA + 2*wid*1024;
  char* dB0 = (char*)lB + 2*wid*1024;

  f32x4 acc[4][4] = {};

  // ---- fragment read offset (sigma of (fr, kq)), bytes within subtile
  const int fr = lane & 15, kq = lane >> 4;
  const int pr = ((((fr ^ ((fr >> 2) & 1)) << 2) | (kq ^ (fr & 3)))) * 16;
  const char* paBase = (const char*)lA + (wr*4)*1024 + pr;
  const char* pbBase = (const char*)lB + (wc*4)*1024 + pr;

  for (int kt = 0; kt < K; kt += 32){
    gload16(gA0 + kt, dA0);
    gload16(gA1 + kt, dA0 + 1024);
    gload16(gB0 + kt, dB0);
    gload16(gB1 + kt, dB0 + 1024);
    __syncthreads();   // compiler drains vmcnt before barrier
    frag8 af[4], bfr[4];
    #pragma unroll
    for (int i = 0; i < 4; i++){
      af[i]  = *reinterpret_cast<const frag8*>(paBase + i*1024);
      bfr[i] = *reinterpret_cast<const frag8*>(pbBase + i*1024);
    }
    #pragma unroll
    for (int i = 0; i < 4; i++)
      #pragma unroll
      for (int j = 0; j < 4; j++)
        acc[i][j] = __builtin_amdgcn_mfma_f32_16x16x32_bf16(af[i], bfr[j], acc[i][j], 0, 0, 0);
    __syncthreads();
  }

  // epilogue: C/D frag layout col=lane&15, row=(lane>>4)*4+r  [m89-verified]
  const int er = (lane >> 4) * 4, ec = lane & 15;
  if (MODE == 0){
    // stage bf16 tile in LDS with chunk-XOR swizzle: chunk c of row stored at
    // slot c ^ (row&15)  -> conflict-free contiguous readback per row.
    #pragma unroll
    for (int j = 0; j < 4; j++){
      const int col = wc*64 + j*16 + ec;
      const float bv = bias[n0 + col];
      const int c = col >> 3, clo = col & 7;
      #pragma unroll
      for (int i = 0; i < 4; i++)
        #pragma unroll
        for (int r = 0; r < 4; r++){
          const int row = wr*64 + i*16 + er + r;
          lC[row*128 + (c ^ (row & 15))*8 + clo] = f2bfu(acc[i][j][r] + bv);
        }
    }
    __syncthreads();
    // readback: 16 lanes cover one full 256B row; 8 iterations cover 128 rows
    const int rl = tid >> 4, co = tid & 15;
    #pragma unroll
    for (int it = 0; it < 8; it++){
      const int row = it*16 + rl;
      uint4 val = *reinterpret_cast<const uint4*>(&lC[row*128 + (co ^ (row & 15))*8]);
      *reinterpret_cast<uint4*>((u16*)Cout + (size_t)(m0 + row) * Ndim + n0 + co*8) = val;
    }
  } else {
    #pragma unroll
    for (int j = 0; j < 4; j++){
      const int col = n0 + wc*64 + j*16 + ec;
      const float bv = bias[col];
      #pragma unroll
      for (int i = 0; i < 4; i++){
        #pragma unroll
        for (int r = 0; r < 4; r++){
          const size_t row = (size_t)(m0 + wr*64 + i*16 + er + r);
          ((float*)Cout)[row * Ndim + col] = acc[i][j][r] + bv + resid[row * Ndim + col];
        }
      }
    }
  }
}

// ---------------- attention over T=16, one wave per (b,h,w,head) ----------------
// qkv row layout per head n: f = n*192 + [0:64)=q [64:128)=k [128:192)=v
// output o (16x64) overwrites the v-slots (already staged to LDS before write).
__global__ __launch_bounds__(64) void attn_kernel(u16* __restrict__ qkv){
  __shared__ __align__(16) u16 sq[16][72];
  __shared__ __align__(16) u16 sk[16][72];
  __shared__ __align__(16) u16 sv[16][72];
  __shared__ float sp[16][17];
  const int lane = threadIdx.x;
  int bid = blockIdx.x;
  const int n = bid % 12; bid /= 12;
  const int w = bid % 32; bid /= 32;
  const int h = bid % 32; const int b = bid / 32;
  u16* base = qkv + ((size_t)(b*16384 + h*32 + w)) * F3 + n * 192;
  const size_t tstride = (size_t)1024 * F3;   // t-step = 1024 rows

  #pragma unroll
  for (int i = 0; i < 6; i++){
    const int e8 = lane + i*64;
    const int t = e8 / 24, ck = e8 % 24;
    uint4 val = *reinterpret_cast<const uint4*>(base + (size_t)t*tstride + ck*8);
    u16* dst = (ck < 8) ? &sq[t][ck*8] : (ck < 16) ? &sk[t][(ck-8)*8] : &sv[t][(ck-16)*8];
    *reinterpret_cast<uint4*>(dst) = val;
  }
  __syncthreads();

  const int g = lane >> 4, sj = lane & 15;
  float accv[4] = {0.f, 0.f, 0.f, 0.f};
  #pragma unroll
  for (int dc = 0; dc < 8; dc++){
    union { uint4 u; u16 s[8]; } kc;
    kc.u = *reinterpret_cast<const uint4*>(&sk[sj][dc*8]);
    #pragma unroll
    for (int i = 0; i < 4; i++){
      union { uint4 u; u16 s[8]; } qc;
      qc.u = *reinterpret_cast<const uint4*>(&sq[g + i*4][dc*8]);
      #pragma unroll
      for (int e = 0; e < 8; e++)
        accv[i] += bfu2f(qc.s[e]) * bfu2f(kc.s[e]);
    }
  }
  #pragma unroll
  for (int i = 0; i < 4; i++){
    float sc = accv[i] * 0.125f;
    float mx = sc;
    #pragma unroll
    for (int o = 1; o < 16; o <<= 1) mx = fmaxf(mx, __shfl_xor(mx, o, 16));
    float p = __expf(sc - mx);
    float sm = p;
    #pragma unroll
    for (int o = 1; o < 16; o <<= 1) sm += __shfl_xor(sm, o, 16);
    sp[g + i*4][sj] = p / sm;
  }
  __syncthreads();

  #pragma unroll
  for (int t = 0; t < 16; t++){
    float o = 0.f;
    #pragma unroll
    for (int s = 0; s < 16; s++) o += sp[t][s] * bfu2f(sv[s][lane]);
    base[(size_t)t*tstride + 128 + lane] = f2bfu(o);
  }
}

// ---------------- LN2: reads attention output from v-slots of qkv ----------------
__global__ __launch_bounds__(256) void ln2_kernel(const u16* __restrict__ qkv,
    const float* __restrict__ w, const float* __restrict__ b, u16* __restrict__ y2){
  const int lane = threadIdx.x & 63, wid = threadIdx.x >> 6;
  const size_t row = (size_t)blockIdx.x * 4 + wid;
  const u16* src = qkv + row * F3 + 128;
  float v[12];
  #pragma unroll
  for (int j = 0; j < 12; j++) v[j] = bfu2f(src[j*192 + lane]);   // c = j*64+lane
  float s = 0.f, ss = 0.f;
  #pragma unroll
  for (int j = 0; j < 12; j++){ s += v[j]; ss += v[j]*v[j]; }
  #pragma unroll
  for (int o = 32; o; o >>= 1){ s += __shfl_xor(s, o, 64); ss += __shfl_xor(ss, o, 64); }
  const float mu = s * (1.f/768.f);
  const float rs = rsqrtf(ss*(1.f/768.f) - mu*mu + LNEPS);
  #pragma unroll
  for (int j = 0; j < 12; j++){
    const int c = j*64 + lane;
    y2[row * C + c] = f2bfu((v[j]-mu)*rs*w[c] + b[c]);
  }
}

extern "C" void kernel_launch(void* const* d_in, const int* in_sizes, int n_in,
                              void* d_out, int out_size, void* d_ws, size_t ws_size,
                              hipStream_t stream){
  const float* x    = (const float*)d_in[0];
  const float* ln1w = (const float*)d_in[1];
  const float* ln1b = (const float*)d_in[2];
  const float* Wqkv = (const float*)d_in[3];
  const float* bqkv = (const float*)d_in[4];
  const float* ln2w = (const float*)d_in[5];
  const float* ln2b = (const float*)d_in[6];
  const float* Wout = (const float*)d_in[7];
  const float* bout = (const float*)d_in[8];
  float* out = (float*)d_out;

  char* ws = (char*)d_ws;
  u16* qkv = (u16*)ws;                       // 32768*2304*2 = 150,994,944 B
  u16* y   = (u16*)(ws + 150994944);         // 32768*768*2  =  50,331,648 B (y1, then y2)
  u16* wq  = (u16*)(ws + 201326592);         // 2304*768*2   =   3,538,944 B
  u16* wo  = (u16*)(ws + 204865536);         // 768*768*2    =   1,179,648 B  (total 206,045,184)

  cvt_bf16<<<(F3*C + 255)/256, 256, 0, stream>>>(Wqkv, wq, F3*C);
  cvt_bf16<<<(C*C + 255)/256, 256, 0, stream>>>(Wout, wo, C*C);
  ln1_kernel<<<MROWS/4, 256, 0, stream>>>(x, ln1w, ln1b, y);
  gemm_bt<0><<<(MROWS/128)*(F3/128), 256, 0, stream>>>(y, wq, bqkv, nullptr, qkv, F3, C);
  attn_kernel<<<2*32*32*12, 64, 0, stream>>>(qkv);
  ln2_kernel<<<MROWS/4, 256, 0, stream>>>(qkv, ln2w, ln2b, y);
  gemm_bt<1><<<(MROWS/128)*(C/128), 256, 0, stream>>>(y, wo, bout, x, out, C, C);
}

// Round 4
// 404.502 us; speedup vs baseline: 1.2102x; 1.0584x over previous
//
#include <hip/hip_runtime.h>

typedef unsigned short u16;
typedef __attribute__((ext_vector_type(8))) short frag8;
typedef __attribute__((ext_vector_type(4))) float f32x4;

static constexpr int C = 768;
static constexpr int F3 = 2304;      // 3*C
static constexpr int MROWS = 32768;  // B*T*H*W
static constexpr float LNEPS = 1e-5f;

__device__ __forceinline__ float bfu2f(u16 u){
  union { unsigned u; float f; } x; x.u = (unsigned)u << 16; return x.f;
}
__device__ __forceinline__ u16 f2bfu(float f){
  union { float f; unsigned u; } x; x.f = f;
  unsigned r = x.u + 0x7fffu + ((x.u >> 16) & 1u);   // RNE bf16
  return (u16)(r >> 16);
}

__device__ __forceinline__ void gload16(const void* g, void* l){
  __builtin_amdgcn_global_load_lds(
      (const __attribute__((address_space(1))) void*)g,
      (__attribute__((address_space(3))) void*)l, 16, 0, 0);
}

// ---------------- fp32 -> bf16 weight conversion ----------------
__global__ __launch_bounds__(256) void cvt_bf16(const float* __restrict__ src,
                                                u16* __restrict__ dst, int n){
  int i = blockIdx.x * 256 + threadIdx.x;
  if (i < n) dst[i] = f2bfu(src[i]);
}

// ---------------- LN1: fp32 x -> bf16 y ----------------
__global__ __launch_bounds__(256) void ln1_kernel(const float* __restrict__ x,
    const float* __restrict__ w, const float* __restrict__ b, u16* __restrict__ y){
  const int lane = threadIdx.x & 63, wid = threadIdx.x >> 6;
  const size_t row = (size_t)blockIdx.x * 4 + wid;
  const float4* xr = reinterpret_cast<const float4*>(x + row * C);
  float v[12];
  #pragma unroll
  for (int j = 0; j < 3; j++){
    float4 t = xr[lane + j*64];
    v[j*4+0]=t.x; v[j*4+1]=t.y; v[j*4+2]=t.z; v[j*4+3]=t.w;
  }
  float s = 0.f, ss = 0.f;
  #pragma unroll
  for (int j = 0; j < 12; j++){ s += v[j]; ss += v[j]*v[j]; }
  #pragma unroll
  for (int o = 32; o; o >>= 1){ s += __shfl_xor(s, o, 64); ss += __shfl_xor(ss, o, 64); }
  const float mu = s * (1.f/768.f);
  const float rs = rsqrtf(ss*(1.f/768.f) - mu*mu + LNEPS);
  ushort4* yr = reinterpret_cast<ushort4*>(y + row * C);
  const float4* wv = reinterpret_cast<const float4*>(w);
  const float4* bv = reinterpret_cast<const float4*>(b);
  #pragma unroll
  for (int j = 0; j < 3; j++){
    float4 wj = wv[lane + j*64], bj = bv[lane + j*64];
    ushort4 o4;
    o4.x = f2bfu((v[j*4+0]-mu)*rs*wj.x + bj.x);
    o4.y = f2bfu((v[j*4+1]-mu)*rs*wj.y + bj.y);
    o4.z = f2bfu((v[j*4+2]-mu)*rs*wj.z + bj.z);
    o4.w = f2bfu((v[j*4+3]-mu)*rs*wj.w + bj.w);
    yr[lane + j*64] = o4;
  }
}

// ---------------- GEMM: C[m,n] = sum_k A[m,k]*B[n,k]  (B^T layout) ----------------
// 256x256 tile, 8 waves (2M x 4N), BK=32, K=768 -> 24 K-tiles.
// LDS ring of 4 buffers x (A 16KB + B 16KB) = 128KB. Pipeline depth 3:
//   per tile t: vmcnt(8); s_barrier; issue loads(t+3 -> buf[(t+3)&3]);
//               ds_read frags buf[t&3]; 32 MFMA.
// Safety: issue-after-barrier (all waves' reads of that buf completed, since
// each wave drains lgkmcnt before its MFMAs and the barrier follows them);
// vmcnt(8) BEFORE the barrier ensures ALL waves' tile-t loads landed.
// Subtile = 16 rows x 32 k = 64 chunks of 16B, sigma-swizzled (R3-verified):
//   slot p = ((r ^ ((r>>2)&1))<<2) | (q ^ (r&3))
//   -> coalesced 64B global segments per lane-quad AND conflict-free ds_read_b128.
// MODE 0: out = bf16(acc + bias)            (qkv projection)
// MODE 1: out = fp32(acc + bias + resid)    (out projection + residual)
template<int MODE>
__global__ __launch_bounds__(512, 2) void gemm_bt(
    const u16* __restrict__ A, const u16* __restrict__ Bw,
    const float* __restrict__ bias, const float* __restrict__ resid,
    void* __restrict__ Cout, int Ndim, int K)
{
  __shared__ __align__(16) char lds[131072];
  const int tid = threadIdx.x;
  const int lane = tid & 63, wid = tid >> 6;
  const int wm = wid >> 2, wn = wid & 3;        // 2 x 4 wave grid
  const int ntn = Ndim >> 8;
  const int cpx = (int)gridDim.x >> 3;          // bijective XCD swizzle (grid%8==0)
  const int wg = ((int)blockIdx.x & 7) * cpx + ((int)blockIdx.x >> 3);
  const int bm = wg / ntn, bn = wg % ntn;
  const int m0 = bm << 8, n0 = bn << 8;

  // staging source decode (sigma^-1): lane -> (row rr, kchunk qq) of a subtile
  const int rp = lane >> 2;
  const int rr = rp ^ ((rp >> 2) & 1);
  const int qq = (lane & 3) ^ (rr & 3);
  const u16* aS0 = A  + (size_t)(m0 + wid*32 + rr) * K + qq*8;
  const u16* bS0 = Bw + (size_t)(n0 + wid*32 + rr) * K + qq*8;
  const size_t rstep = 16 * (size_t)K;

  // fragment read offset within subtile (sigma of (fr,kq)), bytes
  const int fr = lane & 15, kq = lane >> 4;
  const int sig16 = (((fr ^ ((fr >> 2) & 1)) << 2) | (kq ^ (fr & 3))) * 16;

  f32x4 acc[8][4] = {};

  // stage one K-tile st into ring buffer bsel: wave wid covers rows
  // [wid*32, wid*32+32) of both operands = subtiles 2wid, 2wid+1.
  auto stage = [&](int st, int bsel){
    char* lb = lds + bsel*32768 + wid*2048;     // wave-uniform LDS dest base
    const u16* ga = aS0 + st*32;
    const u16* gb = bS0 + st*32;
    gload16(ga,         lb);
    gload16(ga + rstep, lb + 1024);
    gload16(gb,         lb + 16384);
    gload16(gb + rstep, lb + 16384 + 1024);
  };

  stage(0, 0); stage(1, 1); stage(2, 2);        // prologue: 12 loads in flight

  for (int t = 0; t < 24; ++t){
    asm volatile("s_waitcnt vmcnt(8)" ::: "memory");   // tile t fully landed (all waves after barrier)
    __builtin_amdgcn_s_barrier();                      // raw barrier: loads stay in flight
    asm volatile("" ::: "memory");
    int st = t + 3; if (st >= 24) st -= 24;            // wrapped tail keeps vmcnt uniform
    stage(st, st & 3);                                 // (t+3)&3 == st&3 since 24%4==0

    const char* lb = lds + (t & 3)*32768;
    const char* pa = lb + wm*8192 + sig16;
    const char* pb = lb + 16384 + wn*4096 + sig16;
    frag8 bfr[4], af[8];
    #pragma unroll
    for (int nf = 0; nf < 4; nf++) bfr[nf] = *reinterpret_cast<const frag8*>(pb + nf*1024);
    #pragma unroll
    for (int mf = 0; mf < 8; mf++) af[mf] = *reinterpret_cast<const frag8*>(pa + mf*1024);

    __builtin_amdgcn_s_setprio(1);
    #pragma unroll
    for (int mf = 0; mf < 8; mf++)
      #pragma unroll
      for (int nf = 0; nf < 4; nf++)
        acc[mf][nf] = __builtin_amdgcn_mfma_f32_16x16x32_bf16(af[mf], bfr[nf], acc[mf][nf], 0, 0, 0);
    __builtin_amdgcn_s_setprio(0);
  }

  // epilogue: C/D frag layout col=lane&15, row=(lane>>4)*4+r  [m89-verified]
  const int er = (lane >> 4) * 4, ec = lane & 15;
  float bv[4];
  #pragma unroll
  for (int nf = 0; nf < 4; nf++) bv[nf] = bias[n0 + wn*64 + nf*16 + ec];

  if (MODE == 0){
    __syncthreads();   // drains vmcnt(0): tail loads done before LDS reuse
    u16* lC = (u16*)lds;   // 256 rows x 256 cols, chunk-XOR swizzled
    #pragma unroll
    for (int mf = 0; mf < 8; mf++)
      #pragma unroll
      for (int nf = 0; nf < 4; nf++)
        #pragma unroll
        for (int r = 0; r < 4; r++){
          const int row = wm*128 + mf*16 + er + r;
          const int col = wn*64 + nf*16 + ec;
          lC[row*256 + (((col >> 3) ^ (row & 31)) << 3) + (col & 7)] =
              f2bfu(acc[mf][nf][r] + bv[nf]);
        }
    __syncthreads();
    const int r2 = tid >> 1, h = tid & 1;
    u16* gout = (u16*)Cout + (size_t)(m0 + r2) * Ndim + n0;
    #pragma unroll
    for (int q = 0; q < 16; q++){
      const int c = h*16 + q;
      uint4 val = *reinterpret_cast<const uint4*>(&lC[r2*256 + ((c ^ (r2 & 31)) << 3)]);
      *reinterpret_cast<uint4*>(gout + c*8) = val;
    }
  } else {
    asm volatile("s_waitcnt vmcnt(0)" ::: "memory");   // drain tail loads before exit
    float* co = (float*)Cout;
    #pragma unroll
    for (int mf = 0; mf < 8; mf++)
      #pragma unroll
      for (int nf = 0; nf < 4; nf++)
        #pragma unroll
        for (int r = 0; r < 4; r++){
          const size_t row = (size_t)(m0 + wm*128 + mf*16 + er + r);
          const int col = n0 + wn*64 + nf*16 + ec;
          co[row * Ndim + col] = acc[mf][nf][r] + bv[nf] + resid[row * Ndim + col];
        }
  }
}

// ---------------- attention over T=16, one wave per (b,h,w,head) ----------------
// qkv row layout per head n: f = n*192 + [0:64)=q [64:128)=k [128:192)=v
// output o (16x64) overwrites the v-slots (already staged to LDS before write).
__global__ __launch_bounds__(64) void attn_kernel(u16* __restrict__ qkv){
  __shared__ __align__(16) u16 sq[16][72];
  __shared__ __align__(16) u16 sk[16][72];
  __shared__ __align__(16) u16 sv[16][72];
  __shared__ float sp[16][17];
  const int lane = threadIdx.x;
  int bid = blockIdx.x;
  const int n = bid % 12; bid /= 12;
  const int w = bid % 32; bid /= 32;
  const int h = bid % 32; const int b = bid / 32;
  u16* base = qkv + ((size_t)(b*16384 + h*32 + w)) * F3 + n * 192;
  const size_t tstride = (size_t)1024 * F3;   // t-step = 1024 rows

  #pragma unroll
  for (int i = 0; i < 6; i++){
    const int e8 = lane + i*64;
    const int t = e8 / 24, ck = e8 % 24;
    uint4 val = *reinterpret_cast<const uint4*>(base + (size_t)t*tstride + ck*8);
    u16* dst = (ck < 8) ? &sq[t][ck*8] : (ck < 16) ? &sk[t][(ck-8)*8] : &sv[t][(ck-16)*8];
    *reinterpret_cast<uint4*>(dst) = val;
  }
  __syncthreads();

  const int g = lane >> 4, sj = lane & 15;
  float accv[4] = {0.f, 0.f, 0.f, 0.f};
  #pragma unroll
  for (int dc = 0; dc < 8; dc++){
    union { uint4 u; u16 s[8]; } kc;
    kc.u = *reinterpret_cast<const uint4*>(&sk[sj][dc*8]);
    #pragma unroll
    for (int i = 0; i < 4; i++){
      union { uint4 u; u16 s[8]; } qc;
      qc.u = *reinterpret_cast<const uint4*>(&sq[g + i*4][dc*8]);
      #pragma unroll
      for (int e = 0; e < 8; e++)
        accv[i] += bfu2f(qc.s[e]) * bfu2f(kc.s[e]);
    }
  }
  #pragma unroll
  for (int i = 0; i < 4; i++){
    float sc = accv[i] * 0.125f;
    float mx = sc;
    #pragma unroll
    for (int o = 1; o < 16; o <<= 1) mx = fmaxf(mx, __shfl_xor(mx, o, 16));
    float p = __expf(sc - mx);
    float sm = p;
    #pragma unroll
    for (int o = 1; o < 16; o <<= 1) sm += __shfl_xor(sm, o, 16);
    sp[g + i*4][sj] = p / sm;
  }
  __syncthreads();

  #pragma unroll
  for (int t = 0; t < 16; t++){
    float o = 0.f;
    #pragma unroll
    for (int s = 0; s < 16; s++) o += sp[t][s] * bfu2f(sv[s][lane]);
    base[(size_t)t*tstride + 128 + lane] = f2bfu(o);
  }
}

// ---------------- LN2: reads attention output from v-slots of qkv ----------------
__global__ __launch_bounds__(256) void ln2_kernel(const u16* __restrict__ qkv,
    const float* __restrict__ w, const float* __restrict__ b, u16* __restrict__ y2){
  const int lane = threadIdx.x & 63, wid = threadIdx.x >> 6;
  const size_t row = (size_t)blockIdx.x * 4 + wid;
  const u16* src = qkv + row * F3 + 128;
  float v[12];
  #pragma unroll
  for (int j = 0; j < 12; j++) v[j] = bfu2f(src[j*192 + lane]);   // c = j*64+lane
  float s = 0.f, ss = 0.f;
  #pragma unroll
  for (int j = 0; j < 12; j++){ s += v[j]; ss += v[j]*v[j]; }
  #pragma unroll
  for (int o = 32; o; o >>= 1){ s += __shfl_xor(s, o, 64); ss += __shfl_xor(ss, o, 64); }
  const float mu = s * (1.f/768.f);
  const float rs = rsqrtf(ss*(1.f/768.f) - mu*mu + LNEPS);
  #pragma unroll
  for (int j = 0; j < 12; j++){
    const int c = j*64 + lane;
    y2[row * C + c] = f2bfu((v[j]-mu)*rs*w[c] + b[c]);
  }
}

extern "C" void kernel_launch(void* const* d_in, const int* in_sizes, int n_in,
                              void* d_out, int out_size, void* d_ws, size_t ws_size,
                              hipStream_t stream){
  const float* x    = (const float*)d_in[0];
  const float* ln1w = (const float*)d_in[1];
  const float* ln1b = (const float*)d_in[2];
  const float* Wqkv = (const float*)d_in[3];
  const float* bqkv = (const float*)d_in[4];
  const float* ln2w = (const float*)d_in[5];
  const float* ln2b = (const float*)d_in[6];
  const float* Wout = (const float*)d_in[7];
  const float* bout = (const float*)d_in[8];
  float* out = (float*)d_out;

  char* ws = (char*)d_ws;
  u16* qkv = (u16*)ws;                       // 32768*2304*2 = 150,994,944 B
  u16* y   = (u16*)(ws + 150994944);         // 32768*768*2  =  50,331,648 B (y1, then y2)
  u16* wq  = (u16*)(ws + 201326592);         // 2304*768*2   =   3,538,944 B
  u16* wo  = (u16*)(ws + 204865536);         // 768*768*2    =   1,179,648 B  (total 206,045,184)

  cvt_bf16<<<(F3*C + 255)/256, 256, 0, stream>>>(Wqkv, wq, F3*C);
  cvt_bf16<<<(C*C + 255)/256, 256, 0, stream>>>(Wout, wo, C*C);
  ln1_kernel<<<MROWS/4, 256, 0, stream>>>(x, ln1w, ln1b, y);
  gemm_bt<0><<<(MROWS/256)*(F3/256), 512, 0, stream>>>(y, wq, bqkv, nullptr, qkv, F3, C);
  attn_kernel<<<2*32*32*12, 64, 0, stream>>>(qkv);
  ln2_kernel<<<MROWS/4, 256, 0, stream>>>(qkv, ln2w, ln2b, y);
  gemm_bt<1><<<(MROWS/256)*(C/256), 512, 0, stream>>>(y, wo, bout, x, out, C, C);
}

// Round 5
// 394.252 us; speedup vs baseline: 1.2416x; 1.0260x over previous
//
#include <hip/hip_runtime.h>

typedef unsigned short u16;
typedef __attribute__((ext_vector_type(8))) short frag8;
typedef __attribute__((ext_vector_type(4))) float f32x4;

static constexpr int C = 768;
static constexpr int F3 = 2304;      // 3*C
static constexpr int MROWS = 32768;  // B*T*H*W
static constexpr float LNEPS = 1e-5f;

__device__ __forceinline__ float bfu2f(u16 u){
  union { unsigned u; float f; } x; x.u = (unsigned)u << 16; return x.f;
}
__device__ __forceinline__ u16 f2bfu(float f){
  union { float f; unsigned u; } x; x.f = f;
  unsigned r = x.u + 0x7fffu + ((x.u >> 16) & 1u);   // RNE bf16
  return (u16)(r >> 16);
}

__device__ __forceinline__ void gload16(const void* g, void* l){
  __builtin_amdgcn_global_load_lds(
      (const __attribute__((address_space(1))) void*)g,
      (__attribute__((address_space(3))) void*)l, 16, 0, 0);
}

// ---------------- fp32 -> bf16 weight conversion ----------------
__global__ __launch_bounds__(256) void cvt_bf16(const float* __restrict__ src,
                                                u16* __restrict__ dst, int n){
  int i = blockIdx.x * 256 + threadIdx.x;
  if (i < n) dst[i] = f2bfu(src[i]);
}

// ---------------- LN1: fp32 x -> bf16 y ----------------
__global__ __launch_bounds__(256) void ln1_kernel(const float* __restrict__ x,
    const float* __restrict__ w, const float* __restrict__ b, u16* __restrict__ y){
  const int lane = threadIdx.x & 63, wid = threadIdx.x >> 6;
  const size_t row = (size_t)blockIdx.x * 4 + wid;
  const float4* xr = reinterpret_cast<const float4*>(x + row * C);
  float v[12];
  #pragma unroll
  for (int j = 0; j < 3; j++){
    float4 t = xr[lane + j*64];
    v[j*4+0]=t.x; v[j*4+1]=t.y; v[j*4+2]=t.z; v[j*4+3]=t.w;
  }
  float s = 0.f, ss = 0.f;
  #pragma unroll
  for (int j = 0; j < 12; j++){ s += v[j]; ss += v[j]*v[j]; }
  #pragma unroll
  for (int o = 32; o; o >>= 1){ s += __shfl_xor(s, o, 64); ss += __shfl_xor(ss, o, 64); }
  const float mu = s * (1.f/768.f);
  const float rs = rsqrtf(ss*(1.f/768.f) - mu*mu + LNEPS);
  ushort4* yr = reinterpret_cast<ushort4*>(y + row * C);
  const float4* wv = reinterpret_cast<const float4*>(w);
  const float4* bv = reinterpret_cast<const float4*>(b);
  #pragma unroll
  for (int j = 0; j < 3; j++){
    float4 wj = wv[lane + j*64], bj = bv[lane + j*64];
    ushort4 o4;
    o4.x = f2bfu((v[j*4+0]-mu)*rs*wj.x + bj.x);
    o4.y = f2bfu((v[j*4+1]-mu)*rs*wj.y + bj.y);
    o4.z = f2bfu((v[j*4+2]-mu)*rs*wj.z + bj.z);
    o4.w = f2bfu((v[j*4+3]-mu)*rs*wj.w + bj.w);
    yr[lane + j*64] = o4;
  }
}

// ---------------- GEMM: C[m,n] = sum_k A[m,k]*B[n,k]  (B^T layout) ----------------
// BM=128, BN=256, BK=32. 8 waves (2M x 4N), wave tile 64x64 -> 16 MFMA/tile.
// LDS ring of 4 x (A 8KB + B 16KB) = 96KB. Per tile: 3 gloads/thread, depth-3
// lookahead, vmcnt(6) BEFORE the barrier (all waves' tile-t loads landed at
// barrier-pass), stage(t+3) AFTER it (prev reads of that buf done).
// Subtile = 16r x 32k sigma-swizzled (R3/R4-verified): coalesced 64B global
// segments per lane-quad AND conflict-free ds_read_b128.
// MFMA operands SWAPPED: acc[nf][mf] = mfma(bfr,af) -> lane&15 = m index,
// (lane>>4)*4+r = n index: each acc quad = 4 CONSECUTIVE n -> vectorized
// direct global stores (no LDS bounce, no scalar writes).
// MODE 0: out = bf16(acc + bias)            (qkv projection)
// MODE 1: out = fp32(acc + bias + resid)    (out projection + residual)
template<int MODE>
__global__ __launch_bounds__(512, 2) void gemm_bt(
    const u16* __restrict__ A, const u16* __restrict__ Bw,
    const float* __restrict__ bias, const float* __restrict__ resid,
    void* __restrict__ Cout, int Ndim, int K)
{
  __shared__ __align__(16) char lds[98304];
  const int tid = threadIdx.x;
  const int lane = tid & 63, wid = tid >> 6;
  const int wm = wid >> 2, wn = wid & 3;        // 2 x 4 wave grid
  const int ntn = Ndim >> 8;
  const int cpx = (int)gridDim.x >> 3;          // bijective XCD swizzle (grid%8==0)
  const int wg = ((int)blockIdx.x & 7) * cpx + ((int)blockIdx.x >> 3);
  const int bm = wg / ntn, bn = wg % ntn;
  const int m0 = bm << 7, n0 = bn << 8;

  // staging source decode (sigma^-1): lane -> (row rr, kchunk qq) of a subtile
  const int rp = lane >> 2;
  const int rr = rp ^ ((rp >> 2) & 1);
  const int qq = (lane & 3) ^ (rr & 3);
  const u16* aS  = A  + (size_t)(m0 + wid*16 + rr) * K + qq*8;   // A subtile rg=wid
  const u16* bS0 = Bw + (size_t)(n0 + wid*32 + rr) * K + qq*8;   // B rg=2wid
  const u16* bS1 = bS0 + 16*(size_t)K;                            // B rg=2wid+1

  // fragment read offset within subtile (sigma of (fr,kq)), bytes
  const int fr = lane & 15, kq = lane >> 4;
  const int sig16 = (((fr ^ ((fr >> 2) & 1)) << 2) | (kq ^ (fr & 3))) * 16;

  f32x4 acc[4][4] = {};   // [nf][mf] (swapped-operand layout)

  auto stage = [&](int st){
    char* lb = lds + (st & 3) * 24576;
    gload16(aS  + st*32, lb + wid*1024);
    gload16(bS0 + st*32, lb + 8192 + (2*wid)*1024);
    gload16(bS1 + st*32, lb + 8192 + (2*wid+1)*1024);
  };
  stage(0); stage(1); stage(2);        // prologue: 9 loads in flight

  for (int t = 0; t < 24; ++t){
    asm volatile("s_waitcnt vmcnt(6)" ::: "memory");   // tile t landed (all waves, pre-barrier)
    __builtin_amdgcn_s_barrier();
    asm volatile("" ::: "memory");
    int st = t + 3; if (st >= 24) st -= 24;            // wrapped tail keeps vmcnt uniform
    stage(st);                                          // (t+3)&3: prev reads done at barrier

    const char* lb = lds + (t & 3) * 24576;
    const char* pa = lb + (wm*4)*1024 + sig16;          // A rg = wm*4+mf
    const char* pb = lb + 8192 + (wn*4)*1024 + sig16;   // B rg = wn*4+nf
    frag8 af[4], bf4[4];
    #pragma unroll
    for (int mf = 0; mf < 4; mf++) af[mf]  = *reinterpret_cast<const frag8*>(pa + mf*1024);
    #pragma unroll
    for (int nf = 0; nf < 4; nf++) bf4[nf] = *reinterpret_cast<const frag8*>(pb + nf*1024);

    __builtin_amdgcn_s_setprio(1);
    #pragma unroll
    for (int nf = 0; nf < 4; nf++)
      #pragma unroll
      for (int mf = 0; mf < 4; mf++)
        acc[nf][mf] = __builtin_amdgcn_mfma_f32_16x16x32_bf16(bf4[nf], af[mf], acc[nf][mf], 0, 0, 0);
    __builtin_amdgcn_s_setprio(0);
  }

  asm volatile("s_waitcnt vmcnt(0)" ::: "memory");      // drain wrapped tail loads

  // epilogue (swapped layout): m = lane&15 (+16*mf+64*wm), n-quad = (lane>>4)*4 (+16*nf+64*wn)
  const int em = lane & 15, en4 = (lane >> 4) * 4;
  float4 bb[4];
  #pragma unroll
  for (int nf = 0; nf < 4; nf++)
    bb[nf] = *reinterpret_cast<const float4*>(bias + n0 + wn*64 + nf*16 + en4);

  #pragma unroll
  for (int nf = 0; nf < 4; nf++){
    const int n = n0 + wn*64 + nf*16 + en4;
    #pragma unroll
    for (int mf = 0; mf < 4; mf++){
      const size_t m = (size_t)(m0 + wm*64 + mf*16 + em);
      if (MODE == 0){
        ushort4 o4;
        o4.x = f2bfu(acc[nf][mf][0] + bb[nf].x);
        o4.y = f2bfu(acc[nf][mf][1] + bb[nf].y);
        o4.z = f2bfu(acc[nf][mf][2] + bb[nf].z);
        o4.w = f2bfu(acc[nf][mf][3] + bb[nf].w);
        *reinterpret_cast<ushort4*>((u16*)Cout + m * Ndim + n) = o4;
      } else {
        const float4 rr4 = *reinterpret_cast<const float4*>(resid + m * Ndim + n);
        float4 o4;
        o4.x = acc[nf][mf][0] + bb[nf].x + rr4.x;
        o4.y = acc[nf][mf][1] + bb[nf].y + rr4.y;
        o4.z = acc[nf][mf][2] + bb[nf].z + rr4.z;
        o4.w = acc[nf][mf][3] + bb[nf].w + rr4.w;
        *reinterpret_cast<float4*>((float*)Cout + m * Ndim + n) = o4;
      }
    }
  }
}

// ---------------- attention over T=16, one wave per (b,h,w,head) ----------------
// qkv row layout per head n: f = n*192 + [0:64)=q [64:128)=k [128:192)=v
// output o (16x64) overwrites the v-slots (already staged to LDS before write).
__global__ __launch_bounds__(64) void attn_kernel(u16* __restrict__ qkv){
  __shared__ __align__(16) u16 sq[16][72];
  __shared__ __align__(16) u16 sk[16][72];
  __shared__ __align__(16) u16 sv[16][72];
  __shared__ float sp[16][17];
  const int lane = threadIdx.x;
  int bid = blockIdx.x;
  const int n = bid % 12; bid /= 12;
  const int w = bid % 32; bid /= 32;
  const int h = bid % 32; const int b = bid / 32;
  u16* base = qkv + ((size_t)(b*16384 + h*32 + w)) * F3 + n * 192;
  const size_t tstride = (size_t)1024 * F3;   // t-step = 1024 rows

  #pragma unroll
  for (int i = 0; i < 6; i++){
    const int e8 = lane + i*64;
    const int t = e8 / 24, ck = e8 % 24;
    uint4 val = *reinterpret_cast<const uint4*>(base + (size_t)t*tstride + ck*8);
    u16* dst = (ck < 8) ? &sq[t][ck*8] : (ck < 16) ? &sk[t][(ck-8)*8] : &sv[t][(ck-16)*8];
    *reinterpret_cast<uint4*>(dst) = val;
  }
  __syncthreads();

  const int g = lane >> 4, sj = lane & 15;
  float accv[4] = {0.f, 0.f, 0.f, 0.f};
  #pragma unroll
  for (int dc = 0; dc < 8; dc++){
    union { uint4 u; u16 s[8]; } kc;
    kc.u = *reinterpret_cast<const uint4*>(&sk[sj][dc*8]);
    #pragma unroll
    for (int i = 0; i < 4; i++){
      union { uint4 u; u16 s[8]; } qc;
      qc.u = *reinterpret_cast<const uint4*>(&sq[g + i*4][dc*8]);
      #pragma unroll
      for (int e = 0; e < 8; e++)
        accv[i] += bfu2f(qc.s[e]) * bfu2f(kc.s[e]);
    }
  }
  #pragma unroll
  for (int i = 0; i < 4; i++){
    float sc = accv[i] * 0.125f;
    float mx = sc;
    #pragma unroll
    for (int o = 1; o < 16; o <<= 1) mx = fmaxf(mx, __shfl_xor(mx, o, 16));
    float p = __expf(sc - mx);
    float sm = p;
    #pragma unroll
    for (int o = 1; o < 16; o <<= 1) sm += __shfl_xor(sm, o, 16);
    sp[g + i*4][sj] = p / sm;
  }
  __syncthreads();

  #pragma unroll
  for (int t = 0; t < 16; t++){
    float o = 0.f;
    #pragma unroll
    for (int s = 0; s < 16; s++) o += sp[t][s] * bfu2f(sv[s][lane]);
    base[(size_t)t*tstride + 128 + lane] = f2bfu(o);
  }
}

// ---------------- LN2: reads attention output from v-slots of qkv ----------------
__global__ __launch_bounds__(256) void ln2_kernel(const u16* __restrict__ qkv,
    const float* __restrict__ w, const float* __restrict__ b, u16* __restrict__ y2){
  const int lane = threadIdx.x & 63, wid = threadIdx.x >> 6;
  const size_t row = (size_t)blockIdx.x * 4 + wid;
  const u16* src = qkv + row * F3 + 128;
  float v[12];
  #pragma unroll
  for (int j = 0; j < 12; j++) v[j] = bfu2f(src[j*192 + lane]);   // c = j*64+lane
  float s = 0.f, ss = 0.f;
  #pragma unroll
  for (int j = 0; j < 12; j++){ s += v[j]; ss += v[j]*v[j]; }
  #pragma unroll
  for (int o = 32; o; o >>= 1){ s += __shfl_xor(s, o, 64); ss += __shfl_xor(ss, o, 64); }
  const float mu = s * (1.f/768.f);
  const float rs = rsqrtf(ss*(1.f/768.f) - mu*mu + LNEPS);
  #pragma unroll
  for (int j = 0; j < 12; j++){
    const int c = j*64 + lane;
    y2[row * C + c] = f2bfu((v[j]-mu)*rs*w[c] + b[c]);
  }
}

extern "C" void kernel_launch(void* const* d_in, const int* in_sizes, int n_in,
                              void* d_out, int out_size, void* d_ws, size_t ws_size,
                              hipStream_t stream){
  const float* x    = (const float*)d_in[0];
  const float* ln1w = (const float*)d_in[1];
  const float* ln1b = (const float*)d_in[2];
  const float* Wqkv = (const float*)d_in[3];
  const float* bqkv = (const float*)d_in[4];
  const float* ln2w = (const float*)d_in[5];
  const float* ln2b = (const float*)d_in[6];
  const float* Wout = (const float*)d_in[7];
  const float* bout = (const float*)d_in[8];
  float* out = (float*)d_out;

  char* ws = (char*)d_ws;
  u16* qkv = (u16*)ws;                       // 32768*2304*2 = 150,994,944 B
  u16* y   = (u16*)(ws + 150994944);         // 32768*768*2  =  50,331,648 B (y1, then y2)
  u16* wq  = (u16*)(ws + 201326592);         // 2304*768*2   =   3,538,944 B
  u16* wo  = (u16*)(ws + 204865536);         // 768*768*2    =   1,179,648 B  (total 206,045,184)

  cvt_bf16<<<(F3*C + 255)/256, 256, 0, stream>>>(Wqkv, wq, F3*C);
  cvt_bf16<<<(C*C + 255)/256, 256, 0, stream>>>(Wout, wo, C*C);
  ln1_kernel<<<MROWS/4, 256, 0, stream>>>(x, ln1w, ln1b, y);
  gemm_bt<0><<<(MROWS/128)*(F3/256), 512, 0, stream>>>(y, wq, bqkv, nullptr, qkv, F3, C);
  attn_kernel<<<2*32*32*12, 64, 0, stream>>>(qkv);
  ln2_kernel<<<MROWS/4, 256, 0, stream>>>(qkv, ln2w, ln2b, y);
  gemm_bt<1><<<(MROWS/128)*(C/256), 512, 0, stream>>>(y, wo, bout, x, out, C, C);
}